// Round 6
// baseline (223.896 us; speedup 1.0000x reference)
//
#include <hip/hip_runtime.h>

#define HOP 256
#define SEG 1024
#define BLOCK 256

typedef float f32x4 __attribute__((ext_vector_type(4)));

// y[b,i] = x[b,i] * W[pos],  W[pos] = sum_{m=0..3} aw[r+256m]*sw[r+256m]
//   r = pos & 255, blk = pos >> 8, term m included iff blk >= m && blk-m <= kmax.
//
// Evidence (rounds 0-5): all structures land 74-97us with identical traffic;
// NT-load neutral, NT-store and load-batching regressions. Remaining delta vs
// a literal copy: the per-block table build (8 window loads + LDS + sync on
// every one of 32768 blocks). This round: precompute the combined 256-entry
// table ONCE (kernel 1, trivial) into d_ws; the main kernel is then literally
// copy-shaped: NT x-load + L1-hot lane-indexed table load + mul + store.
// This doubles as the pure-copy control: if it still runs ~74us/dispatch,
// that IS the mixed-r/w memory ceiling under this harness's L3 conditioning.

__global__ void SegmenterTensorFlow_28698971472345_build_wt(
    const float* __restrict__ aw,
    const float* __restrict__ sw,
    float* __restrict__ wt)
{
    const int i = threadIdx.x;              // single block of 256
    float acc = 0.f;
#pragma unroll
    for (int m = 0; m < 4; ++m)
        acc += aw[i + m * HOP] * sw[i + m * HOP];
    wt[i] = acc;
}

__global__ __launch_bounds__(BLOCK) void SegmenterTensorFlow_28698971472345_kernel(
    const f32x4* __restrict__ x4,
    const float* __restrict__ aw,
    const float* __restrict__ sw,
    const f32x4* __restrict__ wt4,   // 64 float4s = 256-entry combined table
    f32x4* __restrict__ y4,
    int n_mask,          // N - 1 (N power of two)
    int kmax)            // num_segments - 1 = 8188
{
    const int tid = blockIdx.x * BLOCK + threadIdx.x;

    // Both loads issued back-to-back; x streams (nt neutral but harmless),
    // wt is the same 1KB for every wave -> L1-hot after first generation.
    const f32x4 xv = __builtin_nontemporal_load(&x4[tid]);
    // weight index: (pos>>2)&63 == tid&63 (blockDim=256 => blockIdx*256 = 0 mod 64)
    const f32x4 wi = wt4[tid & 63];

    const int pos = (tid * 4) & n_mask;     // position within the row
    const int blk = pos >> 8;               // wave-uniform (64 lanes * 4 = HOP)

    f32x4 w;
    if (blk >= 3 && blk <= kmax) {
        w = wi;                             // interior: all 4 terms
    } else {
        // edge blocks (6 of 8192 per row), wave-uniform branch: direct sum
        const int r = pos & (HOP - 1);
        float e[4] = {0.f, 0.f, 0.f, 0.f};
#pragma unroll
        for (int m = 0; m < 4; ++m) {
            if (blk >= m && (blk - m) <= kmax) {
#pragma unroll
                for (int j = 0; j < 4; ++j)
                    e[j] += aw[r + j + m * HOP] * sw[r + j + m * HOP];
            }
        }
        w = f32x4{e[0], e[1], e[2], e[3]};
    }

    y4[tid] = xv * w;   // plain store (NT-store was a measured regression)
}

extern "C" void kernel_launch(void* const* d_in, const int* in_sizes, int n_in,
                              void* d_out, int out_size, void* d_ws, size_t ws_size,
                              hipStream_t stream) {
    const float* x  = (const float*)d_in[0];
    const float* aw = (const float*)d_in[1];
    const float* sw = (const float*)d_in[2];
    float* wt = (float*)d_ws;               // 256 floats = 1 KB of workspace

    const int N = 1 << 21;                  // samples per row (power of two)
    const int total4 = out_size / 4;        // 8,388,608 float4s
    const int kmax = (N - SEG) / HOP;       // 8188

    SegmenterTensorFlow_28698971472345_build_wt<<<1, HOP, 0, stream>>>(aw, sw, wt);

    dim3 block(BLOCK);
    dim3 grid(total4 / BLOCK);              // 32768 one-shot blocks
    SegmenterTensorFlow_28698971472345_kernel<<<grid, block, 0, stream>>>(
        (const f32x4*)x, aw, sw, (const f32x4*)wt, (f32x4*)d_out, N - 1, kmax);
}